// Round 7
// baseline (126.347 us; speedup 1.0000x reference)
//
#include <hip/hip_runtime.h>
#include <math.h>

// ---------------------------------------------------------------------------
// xqdaLoss via the N-side Gram. With K = X X^T, Z = class indicator, M = ZZ^T,
// D = diag(c_{t_i}), s = X^T 1, g = Z^T X, u_i = a_i/npos - b_i/nneg:
//   ||T||^2 = Sum K^2, tr(TP) = Sum d_i K^2, ||P||^2 = Sum d_i d_j K^2
//   tr(TG) = ||X g^T||^2, tr(PG) = Sum_i d_i (X g^T)_i^2, ||G||^2 = ||g g^T||^2
//   s^T T s = ||X s||^2, s^T P s = Sum d_i (Xs)_i^2, s^T G s = Sum_a (g_a . s)^2
//   mean-vec norm^2 = u^T K u  (11th invariant, fused into the epilogue)
// ONE symmetric bf16 MFMA Gram of A_ext = [X; g; s; 0-pad] (4608 x 2048).
// k_gram: 256x256 tiles, 8 waves (2Mx4N, wave tile 128x64), BK=64, dbuf.
// K-loop is phase-split (4 quadrants/K-tile): each phase issues the NEXT
// quadrant's ds_reads + a staging pair BEFORE the current quadrant's 16 MFMAs
// (sched_barrier-pinned, setprio'd) so LDS, VMEM and MFMA pipes overlap.
// ---------------------------------------------------------------------------

#define N_ROWS 4096
#define C_DIM  2048
#define NCLS   256
#define RLCAP  96
#define NT128  36      // 128-row blocks in xbf (32 X + 2 g + s/pad + zero)
#define NT2    18      // 256-row blocks for the gram grid
#define NKC    32      // C / 64
#define TILE_B 16384   // xbf tile bytes (128 rows x 64 cols bf16)

typedef __attribute__((ext_vector_type(8))) short short8v;
typedef __attribute__((ext_vector_type(4))) float f32x4;

__device__ __forceinline__ unsigned short f2bf(float f) {
    unsigned u = __float_as_uint(f);
    u += 0x7FFF + ((u >> 16) & 1);   // round-to-nearest-even
    return (unsigned short)(u >> 16);
}

__device__ __forceinline__ void gload16(const void* g, void* l) {
    __builtin_amdgcn_global_load_lds(
        (const __attribute__((address_space(1))) unsigned int*)g,
        (__attribute__((address_space(3))) unsigned int*)l, 16, 0, 0);
}

// swizzled tile byte offset of element (r, c8=col/8): 16B-slot XOR
__device__ __forceinline__ int swz_off(int r, int c8) {
    return r * 128 + ((c8 ^ (r & 7)) << 4);
}

// --- fused per-class kernel: ballot scan + coeffs + class sums + X->bf16 ---
__global__ __launch_bounds__(256) void k_scan_conv(
    const int* __restrict__ t, const float* __restrict__ x,
    float* __restrict__ g, float* __restrict__ ca, float* __restrict__ cb,
    float* __restrict__ dr, float* __restrict__ nposf,
    unsigned char* __restrict__ xbf) {
    __shared__ int ts[N_ROWS];
    __shared__ int rl[RLCAP];
    __shared__ int cnt_s;
    int a = blockIdx.x, tid = threadIdx.x;
    for (int i = tid; i < N_ROWS; i += 256) ts[i] = t[i];
    __syncthreads();
    if (tid < 64) {
        int lane = tid;
        unsigned long long ltmask = (1ULL << lane) - 1ULL;
        int base = 0;
        for (int i0 = 0; i0 < N_ROWS; i0 += 64) {
            int i = i0 + lane;
            bool m = (ts[i] == a);
            unsigned long long mask = __ballot(m);
            if (m) {
                int r = base + (int)__popcll(mask & ltmask);
                if (r < RLCAP) rl[r] = i;
            }
            base += (int)__popcll(mask);
        }
        if (lane == 0) {
            cnt_s = base;
            float cf = (float)base;
            atomicAdd(nposf, 0.5f * cf * (cf - 1.f));
        }
        int cc = base < RLCAP ? base : RLCAP;
        for (int r = lane; r < cc; r += 64) {
            int i = rl[r];
            ca[i] = (float)(2 * r - base + 1);
            cb[i] = (float)(2 * i - 2 * r + base - N_ROWS);
            dr[i] = (float)base;
        }
    }
    __syncthreads();
    int cnt = cnt_s < RLCAP ? cnt_s : RLCAP;
    // column sums + bf16 swizzled conversion over this class's rows
    int c0 = tid * 4, c1 = 1024 + tid * 4;
    float s0=0,s1=0,s2=0,s3=0,s4=0,s5=0,s6=0,s7=0;
    int kc0 = c0 >> 6, c80 = (c0 & 63) >> 3, sb0 = (c0 & 4) << 1;
    int kc1 = c1 >> 6, c81 = (c1 & 63) >> 3, sb1 = (c1 & 4) << 1;
    for (int r = 0; r < cnt; ++r) {
        int i = rl[r];
        const float* row = x + (size_t)i * C_DIM;
        float4 v0 = *(const float4*)(row + c0);
        float4 v1 = *(const float4*)(row + c1);
        s0+=v0.x; s1+=v0.y; s2+=v0.z; s3+=v0.w;
        s4+=v1.x; s5+=v1.y; s6+=v1.z; s7+=v1.w;
        int rb = i >> 7, rr = i & 127;
        unsigned char* tb = xbf + (size_t)rb * NKC * TILE_B;
        int2 w0, w1;
        w0.x = (int)((unsigned)f2bf(v0.x) | ((unsigned)f2bf(v0.y) << 16));
        w0.y = (int)((unsigned)f2bf(v0.z) | ((unsigned)f2bf(v0.w) << 16));
        w1.x = (int)((unsigned)f2bf(v1.x) | ((unsigned)f2bf(v1.y) << 16));
        w1.y = (int)((unsigned)f2bf(v1.z) | ((unsigned)f2bf(v1.w) << 16));
        *(int2*)(tb + (size_t)kc0 * TILE_B + swz_off(rr, c80) + sb0) = w0;
        *(int2*)(tb + (size_t)kc1 * TILE_B + swz_off(rr, c81) + sb1) = w1;
    }
    float* go = g + (size_t)a * C_DIM;
    *(float4*)(go + c0) = make_float4(s0, s1, s2, s3);
    *(float4*)(go + c1) = make_float4(s4, s5, s6, s7);
}

// --- column totals s_c -----------------------------------------------------
__global__ void k_colsum(const float* __restrict__ g, float* __restrict__ s) {
    int c = blockIdx.x * blockDim.x + threadIdx.x;
    float acc = 0.f;
    for (int k = 0; k < NCLS; ++k) acc += g[(size_t)k * C_DIM + c];
    s[c] = acc;
}

// --- convert extension rows (g, s, zero pad) -> row blocks 32..35 ----------
__global__ void k_conv_ext(const float* __restrict__ g, const float* __restrict__ s,
                           unsigned char* __restrict__ xbf) {
    int bx = blockIdx.x;                 // 0..127
    int rb = 32 + (bx >> 5);
    int kc = bx & 31;
    unsigned char* tile = xbf + (size_t)(rb * NKC + kc) * TILE_B;
    int tid = threadIdx.x;
    int r = tid >> 1;
    int half = tid & 1;
    int grow = rb * 128 + r - N_ROWS;    // 0..511
    const float* src = nullptr;
    if (grow < NCLS)        src = g + (size_t)grow * C_DIM + kc * 64;
    else if (grow == NCLS)  src = s + kc * 64;
#pragma unroll
    for (int u = 0; u < 4; ++u) {
        int c8 = half * 4 + u;
        int4 w = make_int4(0, 0, 0, 0);
        if (src) {
            const float4 v0 = *(const float4*)(src + c8 * 8);
            const float4 v1 = *(const float4*)(src + c8 * 8 + 4);
            w.x = (int)((unsigned)f2bf(v0.x) | ((unsigned)f2bf(v0.y) << 16));
            w.y = (int)((unsigned)f2bf(v0.z) | ((unsigned)f2bf(v0.w) << 16));
            w.z = (int)((unsigned)f2bf(v1.x) | ((unsigned)f2bf(v1.y) << 16));
            w.w = (int)((unsigned)f2bf(v1.z) | ((unsigned)f2bf(v1.w) << 16));
        }
        *(int4*)(tile + swz_off(r, c8)) = w;
    }
}

// --- fragment load: row-major swizzled bf16 LDS buffer (256 rows x 128B) ---
__device__ __forceinline__ short8v frag_load(const unsigned char* buf, int rowbase,
                                             int kg, int lane) {
    int row = rowbase + (lane & 15);
    int kgroup = kg + (lane >> 4);
    return *(const short8v*)(buf + row * 128 + ((kgroup ^ (row & 7)) << 4));
}

#define SBAR() __builtin_amdgcn_sched_barrier(0)

// --- extended Gram: 256^2 tiles, 8 waves, phase-split pipelined K-loop -----
__global__ __launch_bounds__(512, 2) void k_gram(
    const unsigned char* __restrict__ xbf, const float* __restrict__ dr,
    const float* __restrict__ ca, const float* __restrict__ cb,
    const float* __restrict__ nposf, float* __restrict__ ssq) {
    // bijective XCD-chunked remap of the 171-block triangle grid (m204)
    const int nwg = NT2 * (NT2 + 1) / 2;     // 171
    int orig = blockIdx.x;
    int q8 = nwg >> 3, r8 = nwg & 7;
    int xcd = orig & 7, loc = orig >> 3;
    int b = (xcd < r8 ? xcd * (q8 + 1) : r8 * (q8 + 1) + (xcd - r8) * q8) + loc;
    int bi = 0;
    while (b >= NT2 - bi) { b -= NT2 - bi; ++bi; }
    int bj = bi + b;
    bool diag = (bi == bj);

    __shared__ __align__(16) unsigned char Ab[2][32768];
    __shared__ __align__(16) unsigned char Bb[2][32768];
    __shared__ float drow[256], dcol[256], urow[256], ucol[256];
    __shared__ float wred[8 * 16];

    int tid = threadIdx.x;
    int lane = tid & 63;
    int w = tid >> 6;          // 0..7
    int wrh = w >> 2;          // row half (0..1) -> rows [128*wrh, +128)
    int wch = w & 3;           // col quarter (0..3) -> cols [64*wch, +64)

    // prologue: stage tile kt=0 into slot 0
#pragma unroll
    for (int u = 0; u < 4; ++u) {
        int inst = 4 * w + u;                       // 0..31, rows 8i..8i+7
        int rb = bi * 2 + (inst >> 4);
        const unsigned char* src =
            xbf + ((size_t)rb * NKC + 0) * TILE_B + (inst & 15) * 1024;
        gload16(src + lane * 16, Ab[0] + inst * 1024);
    }
    if (!diag) {
#pragma unroll
        for (int u = 0; u < 4; ++u) {
            int inst = 4 * w + u;
            int rb = bj * 2 + (inst >> 4);
            const unsigned char* src =
                xbf + ((size_t)rb * NKC + 0) * TILE_B + (inst & 15) * 1024;
            gload16(src + lane * 16, Bb[0] + inst * 1024);
        }
    }
    // preamble overlaps the prologue staging latency
    if (tid < 256) {
        float np = nposf[0];
        float inp = 1.f / np;
        float inn = 1.f / (0.5f * (float)N_ROWS * ((float)N_ROWS - 1.f) - np);
        int gi = bi * 256 + tid;
        bool vi = gi < N_ROWS;
        drow[tid] = vi ? dr[gi] : 0.f;
        urow[tid] = vi ? (ca[gi] * inp - cb[gi] * inn) : 0.f;
        int gj = bj * 256 + tid;
        bool vj = gj < N_ROWS;
        dcol[tid] = vj ? dr[gj] : 0.f;
        ucol[tid] = vj ? (ca[gj] * inp - cb[gj] * inn) : 0.f;
    }

    f32x4 acc[8][4] = {};
    __syncthreads();

    for (int kt = 0; kt < NKC; ++kt) {
        int cur = kt & 1;
        const unsigned char* ab = Ab[cur];
        const unsigned char* bbuf = diag ? Ab[cur] : Bb[cur];
        unsigned char* an = Ab[cur ^ 1];
        unsigned char* bn = Bb[cur ^ 1];
        bool pf = (kt + 1 < NKC);
        const size_t koff = (size_t)(kt + 1) * TILE_B;

        short8v A0[4], A1[4], A2[4], A3[4], B0[4], B1[4];

        // ---- phase 0 issue: quadrant-0 frags (A m0..3 kk0, B n0..3 kk0) ----
#pragma unroll
        for (int m = 0; m < 4; ++m) A0[m] = frag_load(ab, wrh * 128 + m * 16, 0, lane);
#pragma unroll
        for (int n = 0; n < 4; ++n) B0[n] = frag_load(bbuf, wch * 64 + n * 16, 0, lane);
        SBAR();
        if (pf) {                                   // staging pair 0
#pragma unroll
            for (int u = 0; u < 2; ++u) {
                int inst = 4 * w + u;
                int rb = bi * 2 + (inst >> 4);
                gload16(xbf + (size_t)rb * NKC * TILE_B + koff + (inst & 15) * 1024 + lane * 16,
                        an + inst * 1024);
                if (!diag) {
                    int rbb = bj * 2 + (inst >> 4);
                    gload16(xbf + (size_t)rbb * NKC * TILE_B + koff + (inst & 15) * 1024 + lane * 16,
                            bn + inst * 1024);
                }
            }
        }
        SBAR();
        // next-quadrant reads: A m4..7 kk0
#pragma unroll
        for (int m = 0; m < 4; ++m) A1[m] = frag_load(ab, wrh * 128 + (4 + m) * 16, 0, lane);
        SBAR();
        __builtin_amdgcn_s_setprio(1);              // quadrant 0: m0..3 x kk0
#pragma unroll
        for (int m = 0; m < 4; ++m)
#pragma unroll
            for (int n = 0; n < 4; ++n)
                acc[m][n] = __builtin_amdgcn_mfma_f32_16x16x32_bf16(
                    A0[m], B0[n], acc[m][n], 0, 0, 0);
        __builtin_amdgcn_s_setprio(0);
        SBAR();
        if (pf) {                                   // staging pair 1
#pragma unroll
            for (int u = 2; u < 4; ++u) {
                int inst = 4 * w + u;
                int rb = bi * 2 + (inst >> 4);
                gload16(xbf + (size_t)rb * NKC * TILE_B + koff + (inst & 15) * 1024 + lane * 16,
                        an + inst * 1024);
                if (!diag) {
                    int rbb = bj * 2 + (inst >> 4);
                    gload16(xbf + (size_t)rbb * NKC * TILE_B + koff + (inst & 15) * 1024 + lane * 16,
                            bn + inst * 1024);
                }
            }
        }
        SBAR();
        // next-quadrant reads: A m0..3 kk1 + B kk1
#pragma unroll
        for (int m = 0; m < 4; ++m) A2[m] = frag_load(ab, wrh * 128 + m * 16, 4, lane);
#pragma unroll
        for (int n = 0; n < 4; ++n) B1[n] = frag_load(bbuf, wch * 64 + n * 16, 4, lane);
        SBAR();
        __builtin_amdgcn_s_setprio(1);              // quadrant 1: m4..7 x kk0
#pragma unroll
        for (int m = 0; m < 4; ++m)
#pragma unroll
            for (int n = 0; n < 4; ++n)
                acc[4 + m][n] = __builtin_amdgcn_mfma_f32_16x16x32_bf16(
                    A1[m], B0[n], acc[4 + m][n], 0, 0, 0);
        __builtin_amdgcn_s_setprio(0);
        SBAR();
        // next-quadrant reads: A m4..7 kk1
#pragma unroll
        for (int m = 0; m < 4; ++m) A3[m] = frag_load(ab, wrh * 128 + (4 + m) * 16, 4, lane);
        SBAR();
        __builtin_amdgcn_s_setprio(1);              // quadrant 2: m0..3 x kk1
#pragma unroll
        for (int m = 0; m < 4; ++m)
#pragma unroll
            for (int n = 0; n < 4; ++n)
                acc[m][n] = __builtin_amdgcn_mfma_f32_16x16x32_bf16(
                    A2[m], B1[n], acc[m][n], 0, 0, 0);
        __builtin_amdgcn_s_setprio(0);
        SBAR();
        __builtin_amdgcn_s_setprio(1);              // quadrant 3: m4..7 x kk1
#pragma unroll
        for (int m = 0; m < 4; ++m)
#pragma unroll
            for (int n = 0; n < 4; ++n)
                acc[4 + m][n] = __builtin_amdgcn_mfma_f32_16x16x32_bf16(
                    A3[m], B1[n], acc[4 + m][n], 0, 0, 0);
        __builtin_amdgcn_s_setprio(0);
        SBAR();
        __syncthreads();                            // per-tile drain (vm+lgkm)
    }

    // epilogue: region-classified weighted square-sums (11 invariants)
    float fK = diag ? 1.f : 2.f;
    float vs[11] = {0,0,0,0,0,0,0,0,0,0,0};
#pragma unroll
    for (int m = 0; m < 8; ++m) {
#pragma unroll
        for (int qq = 0; qq < 4; ++qq) {
            int iw = wrh * 128 + m * 16 + (lane >> 4) * 4 + qq;
            int gi = bi * 256 + iw;
            float di = drow[iw];
            float ui = urow[iw];
            bool iX = gi < N_ROWS;
            bool iG = !iX && (gi < N_ROWS + NCLS);
            bool iS = gi == N_ROWS + NCLS;
#pragma unroll
            for (int n = 0; n < 4; ++n) {
                int jw = wch * 64 + n * 16 + (lane & 15);
                int gj = bj * 256 + jw;
                float dj = dcol[jw];
                float k = acc[m][n][qq];
                float k2 = k * k;
                bool jX = gj < N_ROWS;
                bool jG = !jX && (gj < N_ROWS + NCLS);
                bool jS = gj == N_ROWS + NCLS;
                if (iX && jX) {
                    vs[0] += fK * k2;                        // Sum K^2
                    vs[1] += 0.5f * fK * (di + dj) * k2;     // Sum d_i K^2
                    vs[2] += fK * di * dj * k2;              // Sum d_i d_j K^2
                    vs[10] += fK * ui * ucol[jw] * k;        // u^T K u
                } else if (iX && jG) {
                    vs[3] += k2;                             // tr(TG)
                    vs[4] += di * k2;                        // tr(PG)
                } else if (iX && jS) {
                    vs[6] += k2;                             // s^T T s
                    vs[7] += di * k2;                        // s^T P s
                } else if (iG && jG) {
                    vs[5] += fK * k2;                        // ||G||^2
                } else if (iG && jS) {
                    vs[8] += k2;                             // s^T G s
                } else if (iS && jS) {
                    vs[9] += k;                              // s^T s
                }
            }
        }
    }
#pragma unroll
    for (int v = 0; v < 11; ++v) {
        float xv = vs[v];
        for (int off = 32; off; off >>= 1) xv += __shfl_down(xv, off);
        if (lane == 0) wred[w * 16 + v] = xv;
    }
    __syncthreads();
    if (tid < 11) {
        float sum = 0.f;
#pragma unroll
        for (int ww = 0; ww < 8; ++ww) sum += wred[ww * 16 + tid];
        atomicAdd(ssq + tid, sum);
    }
}

// --- final assembly --------------------------------------------------------
__global__ void k_final(const float* __restrict__ ssq, const float* __restrict__ nposf,
                        const int* __restrict__ hyper, const int* __restrict__ usemean,
                        const int* __restrict__ use_exp, float* __restrict__ out) {
    if (threadIdx.x != 0) return;
    double S0 = ssq[0], S1 = ssq[1], S2 = ssq[2], R2 = ssq[3], PG = ssq[4];
    double Q2 = ssq[5], TS = ssq[6], PS = ssq[7], GS = ssq[8], SS = ssq[9];
    double U2 = ssq[10];
    double Nf = (double)N_ROWS;
    double ni2 = S2 - 2.0 * PG + Q2;
    double nj2 = Nf * Nf * S0 + S2 + SS * SS + Q2 - 2.0 * Nf * S1
               - 2.0 * Nf * TS + 2.0 * Nf * R2 + 2.0 * PS - 2.0 * PG - 2.0 * GS;
    double trAB = Nf * S1 - S2 - PS + 2.0 * PG - Nf * R2 + GS - Q2;
    double d2 = ni2 - 2.0 * trAB + nj2;
    float norm_i = (float)sqrt(fmax(ni2, 0.0));
    float norm_j = (float)sqrt(fmax(nj2, 0.0));
    float h = (float)hyper[0], um = (float)usemean[0];
    float loss, dist;
    if (use_exp[0]) {
        dist = (float)exp(-sqrt(fmax(d2, 0.0)));
        loss = dist;
    } else {
        float mean_norm = sqrtf((float)C_DIM) * sqrtf(fmaxf((float)U2, 0.f));
        dist = norm_i - h * norm_j - um * mean_norm;
        loss = fmaxf(dist, 0.f);
    }
    out[0] = loss; out[1] = dist; out[2] = norm_i; out[3] = norm_j;
}

extern "C" void kernel_launch(void* const* d_in, const int* in_sizes, int n_in,
                              void* d_out, int out_size, void* d_ws, size_t ws_size,
                              hipStream_t stream) {
    const float* x = (const float*)d_in[0];
    const int* t = (const int*)d_in[1];
    const int* hyper = (const int*)d_in[2];
    const int* usemean = (const int*)d_in[3];
    const int* use_exp = (const int*)d_in[4];
    float* out = (float*)d_out;

    unsigned char* xbf = (unsigned char*)d_ws;
    size_t xbf_bytes = (size_t)NT128 * NKC * TILE_B;   // ~18.9 MB
    float* g     = (float*)(xbf + xbf_bytes);          // 256 x 2048
    float* s     = g + (size_t)NCLS * C_DIM;           // 2048
    float* ca    = s + C_DIM;                          // N
    float* cb    = ca + N_ROWS;                        // N
    float* dr    = cb + N_ROWS;                        // N
    float* ssq   = dr + N_ROWS;                        // 16
    float* nposf = ssq + 16;                           // 1

    // zero atomically-accumulated scalars (ssq + nposf contiguous)
    hipMemsetAsync(ssq, 0, 32 * sizeof(float), stream);

    k_scan_conv<<<NCLS, 256, 0, stream>>>(t, x, g, ca, cb, dr, nposf, xbf);
    k_colsum<<<C_DIM / 256, 256, 0, stream>>>(g, s);
    k_conv_ext<<<128, 256, 0, stream>>>(g, s, xbf);
    k_gram<<<NT2 * (NT2 + 1) / 2, 512, 0, stream>>>(xbf, dr, ca, cb, nposf, ssq);
    k_final<<<1, 64, 0, stream>>>(ssq, nposf, hyper, usemean, use_exp, out);
}

// Round 8
// 112.031 us; speedup vs baseline: 1.1278x; 1.1278x over previous
//
#include <hip/hip_runtime.h>
#include <math.h>

// ---------------------------------------------------------------------------
// xqdaLoss via the N-side Gram. With K = X X^T, Z = class indicator, M = ZZ^T,
// D = diag(c_{t_i}), s = X^T 1, g = Z^T X, u_i = a_i/npos - b_i/nneg:
//   ||T||^2 = Sum K^2, tr(TP) = Sum d_i K^2, ||P||^2 = Sum d_i d_j K^2
//   tr(TG) = ||X g^T||^2, tr(PG) = Sum_i d_i (X g^T)_i^2, ||G||^2 = ||g g^T||^2
//   s^T T s = ||X s||^2, s^T P s = Sum d_i (Xs)_i^2, s^T G s = Sum_a (g_a . s)^2
//   mean-vec norm^2 = u^T K u  (11th invariant, fused into the epilogue)
// ONE symmetric bf16 MFMA Gram of A_ext = [X; g; s; 0-pad] (4608 x 2048).
// k_gram: 256x256 tiles, 8 waves, BK=32, 4-slot circular LDS pipeline with
// COUNTED vmcnt (stage slot t+2 while computing t; wait vmcnt(8), never 0 in
// the main loop; raw s_barrier) so staging latency is hidden 2 steps deep.
// ---------------------------------------------------------------------------

#define N_ROWS 4096
#define C_DIM  2048
#define NCLS   256
#define RLCAP  96
#define NRB    18      // 256-row blocks (16 X + 1 g + 1 s/pad)
#define NKS    64      // K-steps of 32 cols
#define TSB    16384   // xbf tile bytes (256 rows x 32 cols bf16)
#define SLOT_B 32768   // LDS slot: A tile (16 KB) + B tile (16 KB)

typedef __attribute__((ext_vector_type(8))) short short8v;
typedef __attribute__((ext_vector_type(4))) float f32x4;

__device__ __forceinline__ unsigned short f2bf(float f) {
    unsigned u = __float_as_uint(f);
    u += 0x7FFF + ((u >> 16) & 1);   // round-to-nearest-even
    return (unsigned short)(u >> 16);
}

__device__ __forceinline__ void gload16(const void* g, void* l) {
    __builtin_amdgcn_global_load_lds(
        (const __attribute__((address_space(1))) unsigned int*)g,
        (__attribute__((address_space(3))) unsigned int*)l, 16, 0, 0);
}

// swizzled byte offset inside a 256x32 tile: row r (0..255), col-group c8 (0..3)
__device__ __forceinline__ int swz_off(int r, int c8) {
    return r * 64 + ((c8 ^ ((r >> 1) & 3)) << 4);
}

// --- fused per-class kernel: ballot scan + coeffs + class sums + X->bf16 ---
__global__ __launch_bounds__(256) void k_scan_conv(
    const int* __restrict__ t, const float* __restrict__ x,
    float* __restrict__ g, float* __restrict__ ca, float* __restrict__ cb,
    float* __restrict__ dr, float* __restrict__ nposf,
    unsigned char* __restrict__ xbf) {
    __shared__ int ts[N_ROWS];
    __shared__ int rl[RLCAP];
    __shared__ int cnt_s;
    int a = blockIdx.x, tid = threadIdx.x;
    for (int i = tid; i < N_ROWS; i += 256) ts[i] = t[i];
    __syncthreads();
    if (tid < 64) {
        int lane = tid;
        unsigned long long ltmask = (1ULL << lane) - 1ULL;
        int base = 0;
        for (int i0 = 0; i0 < N_ROWS; i0 += 64) {
            int i = i0 + lane;
            bool m = (ts[i] == a);
            unsigned long long mask = __ballot(m);
            if (m) {
                int r = base + (int)__popcll(mask & ltmask);
                if (r < RLCAP) rl[r] = i;
            }
            base += (int)__popcll(mask);
        }
        if (lane == 0) {
            cnt_s = base;
            float cf = (float)base;
            atomicAdd(nposf, 0.5f * cf * (cf - 1.f));
        }
        int cc = base < RLCAP ? base : RLCAP;
        for (int r = lane; r < cc; r += 64) {
            int i = rl[r];
            ca[i] = (float)(2 * r - base + 1);
            cb[i] = (float)(2 * i - 2 * r + base - N_ROWS);
            dr[i] = (float)base;
        }
    }
    __syncthreads();
    int cnt = cnt_s < RLCAP ? cnt_s : RLCAP;
    // column sums + bf16 swizzled conversion over this class's rows
    int c0 = tid * 4, c1 = 1024 + tid * 4;
    float s0=0,s1=0,s2=0,s3=0,s4=0,s5=0,s6=0,s7=0;
    int ks0 = c0 >> 5, c80 = (c0 & 31) >> 3, sb0 = (c0 & 4) << 1;
    int ks1 = c1 >> 5, c81 = (c1 & 31) >> 3, sb1 = (c1 & 4) << 1;
    for (int r = 0; r < cnt; ++r) {
        int i = rl[r];
        const float* row = x + (size_t)i * C_DIM;
        float4 v0 = *(const float4*)(row + c0);
        float4 v1 = *(const float4*)(row + c1);
        s0+=v0.x; s1+=v0.y; s2+=v0.z; s3+=v0.w;
        s4+=v1.x; s5+=v1.y; s6+=v1.z; s7+=v1.w;
        int rb2 = i >> 8, rr = i & 255;
        unsigned char* tb = xbf + (size_t)rb2 * NKS * TSB;
        int2 w0, w1;
        w0.x = (int)((unsigned)f2bf(v0.x) | ((unsigned)f2bf(v0.y) << 16));
        w0.y = (int)((unsigned)f2bf(v0.z) | ((unsigned)f2bf(v0.w) << 16));
        w1.x = (int)((unsigned)f2bf(v1.x) | ((unsigned)f2bf(v1.y) << 16));
        w1.y = (int)((unsigned)f2bf(v1.z) | ((unsigned)f2bf(v1.w) << 16));
        *(int2*)(tb + (size_t)ks0 * TSB + swz_off(rr, c80) + sb0) = w0;
        *(int2*)(tb + (size_t)ks1 * TSB + swz_off(rr, c81) + sb1) = w1;
    }
    float* go = g + (size_t)a * C_DIM;
    *(float4*)(go + c0) = make_float4(s0, s1, s2, s3);
    *(float4*)(go + c1) = make_float4(s4, s5, s6, s7);
}

// --- column totals s_c -----------------------------------------------------
__global__ void k_colsum(const float* __restrict__ g, float* __restrict__ s) {
    int c = blockIdx.x * blockDim.x + threadIdx.x;
    float acc = 0.f;
    for (int k = 0; k < NCLS; ++k) acc += g[(size_t)k * C_DIM + c];
    s[c] = acc;
}

// --- convert extension rows (g, s, zero pad) -> row blocks 16..17 ----------
__global__ void k_conv_ext(const float* __restrict__ g, const float* __restrict__ s,
                           unsigned char* __restrict__ xbf) {
    int bx = blockIdx.x;                 // 0..127
    int rbe = bx >> 6;                   // 0..1
    int ks = bx & 63;
    unsigned char* tile = xbf + ((size_t)(16 + rbe) * NKS + ks) * TSB;
    int rr = threadIdx.x;                // 0..255
    int grow = rbe * 256 + rr;           // 0..511
    const float* src = nullptr;
    if (grow < NCLS)        src = g + (size_t)grow * C_DIM + ks * 32;
    else if (grow == NCLS)  src = s + ks * 32;
#pragma unroll
    for (int c8 = 0; c8 < 4; ++c8) {
        int4 w = make_int4(0, 0, 0, 0);
        if (src) {
            const float4 v0 = *(const float4*)(src + c8 * 8);
            const float4 v1 = *(const float4*)(src + c8 * 8 + 4);
            w.x = (int)((unsigned)f2bf(v0.x) | ((unsigned)f2bf(v0.y) << 16));
            w.y = (int)((unsigned)f2bf(v0.z) | ((unsigned)f2bf(v0.w) << 16));
            w.z = (int)((unsigned)f2bf(v1.x) | ((unsigned)f2bf(v1.y) << 16));
            w.w = (int)((unsigned)f2bf(v1.z) | ((unsigned)f2bf(v1.w) << 16));
        }
        *(int4*)(tile + swz_off(rr, c8)) = w;
    }
}

// --- fragment load: 256x32 swizzled bf16 tile, full 64-B row per frag ------
__device__ __forceinline__ short8v frag64(const unsigned char* buf, int row0,
                                          int lane) {
    int r = row0 + (lane & 15);
    int c8 = lane >> 4;
    return *(const short8v*)(buf + swz_off(r, c8));
}

// --- extended Gram: 4-slot circular pipeline, counted vmcnt ----------------
__global__ __launch_bounds__(512, 2) void k_gram(
    const unsigned char* __restrict__ xbf, const float* __restrict__ dr,
    const float* __restrict__ ca, const float* __restrict__ cb,
    const float* __restrict__ nposf, float* __restrict__ ssq) {
    // bijective XCD-chunked remap of the 171-block triangle grid (m204)
    const int nwg = NRB * (NRB + 1) / 2;     // 171
    int orig = blockIdx.x;
    int q8 = nwg >> 3, r8 = nwg & 7;
    int xcd = orig & 7, loc = orig >> 3;
    int b = (xcd < r8 ? xcd * (q8 + 1) : r8 * (q8 + 1) + (xcd - r8) * q8) + loc;
    int bi = 0;
    while (b >= NRB - bi) { b -= NRB - bi; ++bi; }
    int bj = bi + b;
    bool diag = (bi == bj);

    __shared__ __align__(16) unsigned char Sl[4][SLOT_B];
    __shared__ float drow[256], dcol[256], urow[256], ucol[256];
    __shared__ float wred[8 * 16];

    int tid = threadIdx.x;
    int lane = tid & 63;
    int w = tid >> 6;          // 0..7
    int wrh = w >> 2;          // row half -> rows [128*wrh, +128)
    int wch = w & 3;           // col quarter -> cols [64*wch, +64)

    const unsigned char* abase = xbf + (size_t)bi * NKS * TSB;
    const unsigned char* bbase = xbf + (size_t)bj * NKS * TSB;
    int off0 = w * 2048 + lane * 16;

    // prologue: stage steps 0,1 into slots 0,1 (diag stages A twice: uniform)
#pragma unroll
    for (int p = 0; p < 2; ++p) {
        const unsigned char* at = abase + (size_t)p * TSB;
        const unsigned char* bt = bbase + (size_t)p * TSB;
#pragma unroll
        for (int u = 0; u < 2; ++u) {
            gload16(at + off0 + u * 1024, Sl[p] + off0 + u * 1024);
            gload16(bt + off0 + u * 1024, Sl[p] + 16384 + off0 + u * 1024);
        }
    }
    // preamble overlaps the prologue staging latency
    if (tid < 256) {
        float np = nposf[0];
        float inp = 1.f / np;
        float inn = 1.f / (0.5f * (float)N_ROWS * ((float)N_ROWS - 1.f) - np);
        int gi = bi * 256 + tid;
        bool vi = gi < N_ROWS;
        drow[tid] = vi ? dr[gi] : 0.f;
        urow[tid] = vi ? (ca[gi] * inp - cb[gi] * inn) : 0.f;
        int gj = bj * 256 + tid;
        bool vj = gj < N_ROWS;
        dcol[tid] = vj ? dr[gj] : 0.f;
        ucol[tid] = vj ? (ca[gj] * inp - cb[gj] * inn) : 0.f;
    }

    f32x4 acc[8][4] = {};
    __syncthreads();           // full drain once: slots 0,1 landed, preamble visible

#define STAGE_STEP(ks)                                                         \
    {                                                                          \
        const unsigned char* at = abase + (size_t)(ks) * TSB;                  \
        const unsigned char* bt = bbase + (size_t)(ks) * TSB;                  \
        unsigned char* sl = Sl[(ks) & 3];                                      \
        _Pragma("unroll")                                                      \
        for (int u = 0; u < 2; ++u) {                                          \
            gload16(at + off0 + u * 1024, sl + off0 + u * 1024);               \
            gload16(bt + off0 + u * 1024, sl + 16384 + off0 + u * 1024);       \
        }                                                                      \
    }

#define COMPUTE_STEP(t)                                                        \
    {                                                                          \
        const unsigned char* sb = Sl[(t) & 3];                                 \
        short8v A[8], B[4];                                                    \
        _Pragma("unroll")                                                      \
        for (int m = 0; m < 8; ++m) A[m] = frag64(sb, wrh * 128 + m * 16, lane);\
        _Pragma("unroll")                                                      \
        for (int n = 0; n < 4; ++n) B[n] = frag64(sb + 16384, wch * 64 + n * 16, lane);\
        __builtin_amdgcn_s_setprio(1);                                         \
        _Pragma("unroll")                                                      \
        for (int m = 0; m < 8; ++m)                                            \
            _Pragma("unroll")                                                  \
            for (int n = 0; n < 4; ++n)                                        \
                acc[m][n] = __builtin_amdgcn_mfma_f32_16x16x32_bf16(           \
                    A[m], B[n], acc[m][n], 0, 0, 0);                           \
        __builtin_amdgcn_s_setprio(0);                                         \
    }

    // main loop: stage t+2, wait with 2 steps (8 gloads) still in flight
    for (int t = 0; t < NKS - 2; ++t) {
        STAGE_STEP(t + 2);
        asm volatile("s_waitcnt vmcnt(8)" ::: "memory");
        asm volatile("s_barrier" ::: "memory");
        COMPUTE_STEP(t);
    }
    // tail: t = NKS-2, NKS-1
    asm volatile("s_waitcnt vmcnt(4)" ::: "memory");
    asm volatile("s_barrier" ::: "memory");
    COMPUTE_STEP(NKS - 2);
    asm volatile("s_waitcnt vmcnt(0)" ::: "memory");
    asm volatile("s_barrier" ::: "memory");
    COMPUTE_STEP(NKS - 1);

    // epilogue: region-classified weighted square-sums (11 invariants)
    float fK = diag ? 1.f : 2.f;
    float vs[11] = {0,0,0,0,0,0,0,0,0,0,0};
#pragma unroll
    for (int m = 0; m < 8; ++m) {
#pragma unroll
        for (int qq = 0; qq < 4; ++qq) {
            int iw = wrh * 128 + m * 16 + (lane >> 4) * 4 + qq;
            int gi = bi * 256 + iw;
            float di = drow[iw];
            float ui = urow[iw];
            bool iX = gi < N_ROWS;
            bool iG = !iX && (gi < N_ROWS + NCLS);
            bool iS = gi == N_ROWS + NCLS;
#pragma unroll
            for (int n = 0; n < 4; ++n) {
                int jw = wch * 64 + n * 16 + (lane & 15);
                int gj = bj * 256 + jw;
                float dj = dcol[jw];
                float k = acc[m][n][qq];
                float k2 = k * k;
                bool jX = gj < N_ROWS;
                bool jG = !jX && (gj < N_ROWS + NCLS);
                bool jS = gj == N_ROWS + NCLS;
                if (iX && jX) {
                    vs[0] += fK * k2;                        // Sum K^2
                    vs[1] += 0.5f * fK * (di + dj) * k2;     // Sum d_i K^2
                    vs[2] += fK * di * dj * k2;              // Sum d_i d_j K^2
                    vs[10] += fK * ui * ucol[jw] * k;        // u^T K u
                } else if (iX && jG) {
                    vs[3] += k2;                             // tr(TG)
                    vs[4] += di * k2;                        // tr(PG)
                } else if (iX && jS) {
                    vs[6] += k2;                             // s^T T s
                    vs[7] += di * k2;                        // s^T P s
                } else if (iG && jG) {
                    vs[5] += fK * k2;                        // ||G||^2
                } else if (iG && jS) {
                    vs[8] += k2;                             // s^T G s
                } else if (iS && jS) {
                    vs[9] += k;                              // s^T s
                }
            }
        }
    }
#pragma unroll
    for (int v = 0; v < 11; ++v) {
        float xv = vs[v];
        for (int off = 32; off; off >>= 1) xv += __shfl_down(xv, off);
        if (lane == 0) wred[w * 16 + v] = xv;
    }
    __syncthreads();
    if (tid < 11) {
        float sum = 0.f;
#pragma unroll
        for (int ww = 0; ww < 8; ++ww) sum += wred[ww * 16 + tid];
        atomicAdd(ssq + tid, sum);
    }
}

// --- final assembly --------------------------------------------------------
__global__ void k_final(const float* __restrict__ ssq, const float* __restrict__ nposf,
                        const int* __restrict__ hyper, const int* __restrict__ usemean,
                        const int* __restrict__ use_exp, float* __restrict__ out) {
    if (threadIdx.x != 0) return;
    double S0 = ssq[0], S1 = ssq[1], S2 = ssq[2], R2 = ssq[3], PG = ssq[4];
    double Q2 = ssq[5], TS = ssq[6], PS = ssq[7], GS = ssq[8], SS = ssq[9];
    double U2 = ssq[10];
    double Nf = (double)N_ROWS;
    double ni2 = S2 - 2.0 * PG + Q2;
    double nj2 = Nf * Nf * S0 + S2 + SS * SS + Q2 - 2.0 * Nf * S1
               - 2.0 * Nf * TS + 2.0 * Nf * R2 + 2.0 * PS - 2.0 * PG - 2.0 * GS;
    double trAB = Nf * S1 - S2 - PS + 2.0 * PG - Nf * R2 + GS - Q2;
    double d2 = ni2 - 2.0 * trAB + nj2;
    float norm_i = (float)sqrt(fmax(ni2, 0.0));
    float norm_j = (float)sqrt(fmax(nj2, 0.0));
    float h = (float)hyper[0], um = (float)usemean[0];
    float loss, dist;
    if (use_exp[0]) {
        dist = (float)exp(-sqrt(fmax(d2, 0.0)));
        loss = dist;
    } else {
        float mean_norm = sqrtf((float)C_DIM) * sqrtf(fmaxf((float)U2, 0.f));
        dist = norm_i - h * norm_j - um * mean_norm;
        loss = fmaxf(dist, 0.f);
    }
    out[0] = loss; out[1] = dist; out[2] = norm_i; out[3] = norm_j;
}

extern "C" void kernel_launch(void* const* d_in, const int* in_sizes, int n_in,
                              void* d_out, int out_size, void* d_ws, size_t ws_size,
                              hipStream_t stream) {
    const float* x = (const float*)d_in[0];
    const int* t = (const int*)d_in[1];
    const int* hyper = (const int*)d_in[2];
    const int* usemean = (const int*)d_in[3];
    const int* use_exp = (const int*)d_in[4];
    float* out = (float*)d_out;

    unsigned char* xbf = (unsigned char*)d_ws;
    size_t xbf_bytes = (size_t)NRB * NKS * TSB;        // ~18.9 MB
    float* g     = (float*)(xbf + xbf_bytes);          // 256 x 2048
    float* s     = g + (size_t)NCLS * C_DIM;           // 2048
    float* ca    = s + C_DIM;                          // N
    float* cb    = ca + N_ROWS;                        // N
    float* dr    = cb + N_ROWS;                        // N
    float* ssq   = dr + N_ROWS;                        // 16
    float* nposf = ssq + 16;                           // 1

    // zero atomically-accumulated scalars (ssq + nposf contiguous)
    hipMemsetAsync(ssq, 0, 32 * sizeof(float), stream);

    k_scan_conv<<<NCLS, 256, 0, stream>>>(t, x, g, ca, cb, dr, nposf, xbf);
    k_colsum<<<C_DIM / 256, 256, 0, stream>>>(g, s);
    k_conv_ext<<<128, 256, 0, stream>>>(g, s, xbf);
    k_gram<<<NRB * (NRB + 1) / 2, 512, 0, stream>>>(xbf, dr, ca, cb, nposf, ssq);
    k_final<<<1, 64, 0, stream>>>(ssq, nposf, hyper, usemean, use_exp, out);
}

// Round 9
// 97.270 us; speedup vs baseline: 1.2989x; 1.1518x over previous
//
#include <hip/hip_runtime.h>
#include <math.h>

// ---------------------------------------------------------------------------
// xqdaLoss via the N-side Gram. With K = X X^T, Z = class indicator, M = ZZ^T,
// D = diag(c_{t_i}), s = X^T 1, g = Z^T X, u_i = a_i/npos - b_i/nneg:
//   ||T||^2 = Sum K^2, tr(TP) = Sum d_i K^2, ||P||^2 = Sum d_i d_j K^2
//   tr(TG) = ||X g^T||^2, tr(PG) = Sum_i d_i (X g^T)_i^2, ||G||^2 = ||g g^T||^2
//   s^T T s = ||X s||^2, s^T P s = Sum d_i (Xs)_i^2, s^T G s = Sum_a (g_a . s)^2
//   mean-vec norm^2 = u^T K u  (11th invariant, fused into the epilogue)
// ONE symmetric bf16 MFMA Gram of A_ext = [X; g; s; 0-pad] (4608 x 2048).
// k_gram: 256x256 tiles, 16 waves (4Mx4N, wave tile 64x64) = 4 waves/SIMD
// (grid 171 < 256 CUs, so extra waves/SIMD must come from block size);
// BK=32, 4-slot circular LDS pipeline with COUNTED vmcnt (stage slot t+2
// while computing t; wait vmcnt(4), never 0 in the main loop; raw s_barrier).
// ---------------------------------------------------------------------------

#define N_ROWS 4096
#define C_DIM  2048
#define NCLS   256
#define RLCAP  96
#define NRB    18      // 256-row blocks (16 X + 1 g + 1 s/pad)
#define NKS    64      // K-steps of 32 cols
#define TSB    16384   // xbf tile bytes (256 rows x 32 cols bf16)
#define SLOT_B 32768   // LDS slot: A tile (16 KB) + B tile (16 KB)

typedef __attribute__((ext_vector_type(8))) short short8v;
typedef __attribute__((ext_vector_type(4))) float f32x4;

__device__ __forceinline__ unsigned short f2bf(float f) {
    unsigned u = __float_as_uint(f);
    u += 0x7FFF + ((u >> 16) & 1);   // round-to-nearest-even
    return (unsigned short)(u >> 16);
}

__device__ __forceinline__ void gload16(const void* g, void* l) {
    __builtin_amdgcn_global_load_lds(
        (const __attribute__((address_space(1))) unsigned int*)g,
        (__attribute__((address_space(3))) unsigned int*)l, 16, 0, 0);
}

// swizzled byte offset inside a 256x32 tile: row r (0..255), col-group c8 (0..3)
__device__ __forceinline__ int swz_off(int r, int c8) {
    return r * 64 + ((c8 ^ ((r >> 1) & 3)) << 4);
}

// --- fused per-class kernel: ballot scan + coeffs + class sums + X->bf16 ---
__global__ __launch_bounds__(256) void k_scan_conv(
    const int* __restrict__ t, const float* __restrict__ x,
    float* __restrict__ g, float* __restrict__ ca, float* __restrict__ cb,
    float* __restrict__ dr, float* __restrict__ nposf,
    unsigned char* __restrict__ xbf) {
    __shared__ int ts[N_ROWS];
    __shared__ int rl[RLCAP];
    __shared__ int cnt_s;
    int a = blockIdx.x, tid = threadIdx.x;
    for (int i = tid; i < N_ROWS; i += 256) ts[i] = t[i];
    __syncthreads();
    if (tid < 64) {
        int lane = tid;
        unsigned long long ltmask = (1ULL << lane) - 1ULL;
        int base = 0;
        for (int i0 = 0; i0 < N_ROWS; i0 += 64) {
            int i = i0 + lane;
            bool m = (ts[i] == a);
            unsigned long long mask = __ballot(m);
            if (m) {
                int r = base + (int)__popcll(mask & ltmask);
                if (r < RLCAP) rl[r] = i;
            }
            base += (int)__popcll(mask);
        }
        if (lane == 0) {
            cnt_s = base;
            float cf = (float)base;
            atomicAdd(nposf, 0.5f * cf * (cf - 1.f));
        }
        int cc = base < RLCAP ? base : RLCAP;
        for (int r = lane; r < cc; r += 64) {
            int i = rl[r];
            ca[i] = (float)(2 * r - base + 1);
            cb[i] = (float)(2 * i - 2 * r + base - N_ROWS);
            dr[i] = (float)base;
        }
    }
    __syncthreads();
    int cnt = cnt_s < RLCAP ? cnt_s : RLCAP;
    // column sums + bf16 swizzled conversion over this class's rows
    int c0 = tid * 4, c1 = 1024 + tid * 4;
    float s0=0,s1=0,s2=0,s3=0,s4=0,s5=0,s6=0,s7=0;
    int ks0 = c0 >> 5, c80 = (c0 & 31) >> 3, sb0 = (c0 & 4) << 1;
    int ks1 = c1 >> 5, c81 = (c1 & 31) >> 3, sb1 = (c1 & 4) << 1;
    for (int r = 0; r < cnt; ++r) {
        int i = rl[r];
        const float* row = x + (size_t)i * C_DIM;
        float4 v0 = *(const float4*)(row + c0);
        float4 v1 = *(const float4*)(row + c1);
        s0+=v0.x; s1+=v0.y; s2+=v0.z; s3+=v0.w;
        s4+=v1.x; s5+=v1.y; s6+=v1.z; s7+=v1.w;
        int rb2 = i >> 8, rr = i & 255;
        unsigned char* tb = xbf + (size_t)rb2 * NKS * TSB;
        int2 w0, w1;
        w0.x = (int)((unsigned)f2bf(v0.x) | ((unsigned)f2bf(v0.y) << 16));
        w0.y = (int)((unsigned)f2bf(v0.z) | ((unsigned)f2bf(v0.w) << 16));
        w1.x = (int)((unsigned)f2bf(v1.x) | ((unsigned)f2bf(v1.y) << 16));
        w1.y = (int)((unsigned)f2bf(v1.z) | ((unsigned)f2bf(v1.w) << 16));
        *(int2*)(tb + (size_t)ks0 * TSB + swz_off(rr, c80) + sb0) = w0;
        *(int2*)(tb + (size_t)ks1 * TSB + swz_off(rr, c81) + sb1) = w1;
    }
    float* go = g + (size_t)a * C_DIM;
    *(float4*)(go + c0) = make_float4(s0, s1, s2, s3);
    *(float4*)(go + c1) = make_float4(s4, s5, s6, s7);
}

// --- column totals s_c -----------------------------------------------------
__global__ void k_colsum(const float* __restrict__ g, float* __restrict__ s) {
    int c = blockIdx.x * blockDim.x + threadIdx.x;
    float acc = 0.f;
    for (int k = 0; k < NCLS; ++k) acc += g[(size_t)k * C_DIM + c];
    s[c] = acc;
}

// --- convert extension rows (g, s, zero pad) -> row blocks 16..17 ----------
__global__ void k_conv_ext(const float* __restrict__ g, const float* __restrict__ s,
                           unsigned char* __restrict__ xbf) {
    int bx = blockIdx.x;                 // 0..127
    int rbe = bx >> 6;                   // 0..1
    int ks = bx & 63;
    unsigned char* tile = xbf + ((size_t)(16 + rbe) * NKS + ks) * TSB;
    int rr = threadIdx.x;                // 0..255
    int grow = rbe * 256 + rr;           // 0..511
    const float* src = nullptr;
    if (grow < NCLS)        src = g + (size_t)grow * C_DIM + ks * 32;
    else if (grow == NCLS)  src = s + ks * 32;
#pragma unroll
    for (int c8 = 0; c8 < 4; ++c8) {
        int4 w = make_int4(0, 0, 0, 0);
        if (src) {
            const float4 v0 = *(const float4*)(src + c8 * 8);
            const float4 v1 = *(const float4*)(src + c8 * 8 + 4);
            w.x = (int)((unsigned)f2bf(v0.x) | ((unsigned)f2bf(v0.y) << 16));
            w.y = (int)((unsigned)f2bf(v0.z) | ((unsigned)f2bf(v0.w) << 16));
            w.z = (int)((unsigned)f2bf(v1.x) | ((unsigned)f2bf(v1.y) << 16));
            w.w = (int)((unsigned)f2bf(v1.z) | ((unsigned)f2bf(v1.w) << 16));
        }
        *(int4*)(tile + swz_off(rr, c8)) = w;
    }
}

// --- fragment load: 256x32 swizzled bf16 tile, full 64-B row per frag ------
__device__ __forceinline__ short8v frag64(const unsigned char* buf, int row0,
                                          int lane) {
    int r = row0 + (lane & 15);
    int c8 = lane >> 4;
    return *(const short8v*)(buf + swz_off(r, c8));
}

// --- extended Gram: 16 waves (4/SIMD), 4-slot pipeline, counted vmcnt ------
__global__ __launch_bounds__(1024, 4) void k_gram(
    const unsigned char* __restrict__ xbf, const float* __restrict__ dr,
    const float* __restrict__ ca, const float* __restrict__ cb,
    const float* __restrict__ nposf, float* __restrict__ ssq) {
    // bijective XCD-chunked remap of the 171-block triangle grid (m204)
    const int nwg = NRB * (NRB + 1) / 2;     // 171
    int orig = blockIdx.x;
    int q8 = nwg >> 3, r8 = nwg & 7;
    int xcd = orig & 7, loc = orig >> 3;
    int b = (xcd < r8 ? xcd * (q8 + 1) : r8 * (q8 + 1) + (xcd - r8) * q8) + loc;
    int bi = 0;
    while (b >= NRB - bi) { b -= NRB - bi; ++bi; }
    int bj = bi + b;
    bool diag = (bi == bj);

    __shared__ __align__(16) unsigned char Sl[4][SLOT_B];
    __shared__ float drow[256], dcol[256], urow[256], ucol[256];
    __shared__ float wred[16 * 16];

    int tid = threadIdx.x;
    int lane = tid & 63;
    int w = tid >> 6;          // 0..15
    int wr4 = w >> 2;          // row quarter -> rows [64*wr4, +64)
    int wc4 = w & 3;           // col quarter -> cols [64*wc4, +64)

    const unsigned char* abase = xbf + (size_t)bi * NKS * TSB;
    const unsigned char* bbase = xbf + (size_t)bj * NKS * TSB;
    int off0 = w * 1024 + lane * 16;     // 16 waves x 1KB cover a 16KB tile

    // prologue: stage steps 0,1 into slots 0,1 (diag stages A twice: uniform)
#pragma unroll
    for (int p = 0; p < 2; ++p) {
        gload16(abase + (size_t)p * TSB + off0, Sl[p] + off0);
        gload16(bbase + (size_t)p * TSB + off0, Sl[p] + 16384 + off0);
    }
    // preamble overlaps the prologue staging latency
    if (tid < 256) {
        float np = nposf[0];
        float inp = 1.f / np;
        float inn = 1.f / (0.5f * (float)N_ROWS * ((float)N_ROWS - 1.f) - np);
        int gi = bi * 256 + tid;
        bool vi = gi < N_ROWS;
        drow[tid] = vi ? dr[gi] : 0.f;
        urow[tid] = vi ? (ca[gi] * inp - cb[gi] * inn) : 0.f;
        int gj = bj * 256 + tid;
        bool vj = gj < N_ROWS;
        dcol[tid] = vj ? dr[gj] : 0.f;
        ucol[tid] = vj ? (ca[gj] * inp - cb[gj] * inn) : 0.f;
    }

    f32x4 acc[4][4] = {};
    __syncthreads();           // full drain once: slots 0,1 landed, preamble visible

#define STAGE_STEP(ks)                                                         \
    {                                                                          \
        unsigned char* sl = Sl[(ks) & 3];                                      \
        gload16(abase + (size_t)(ks) * TSB + off0, sl + off0);                 \
        gload16(bbase + (size_t)(ks) * TSB + off0, sl + 16384 + off0);         \
    }

#define COMPUTE_STEP(t)                                                        \
    {                                                                          \
        const unsigned char* sb = Sl[(t) & 3];                                 \
        short8v A[4], B[4];                                                    \
        _Pragma("unroll")                                                      \
        for (int m = 0; m < 4; ++m) A[m] = frag64(sb, wr4 * 64 + m * 16, lane);\
        _Pragma("unroll")                                                      \
        for (int n = 0; n < 4; ++n) B[n] = frag64(sb + 16384, wc4 * 64 + n * 16, lane);\
        __builtin_amdgcn_s_setprio(1);                                         \
        _Pragma("unroll")                                                      \
        for (int m = 0; m < 4; ++m)                                            \
            _Pragma("unroll")                                                  \
            for (int n = 0; n < 4; ++n)                                        \
                acc[m][n] = __builtin_amdgcn_mfma_f32_16x16x32_bf16(           \
                    A[m], B[n], acc[m][n], 0, 0, 0);                           \
        __builtin_amdgcn_s_setprio(0);                                         \
    }

    // main loop: stage t+2, wait with 2 steps (4 gloads) still in flight
    for (int t = 0; t < NKS - 2; ++t) {
        STAGE_STEP(t + 2);
        asm volatile("s_waitcnt vmcnt(4)" ::: "memory");
        asm volatile("s_barrier" ::: "memory");
        COMPUTE_STEP(t);
    }
    // tail: t = NKS-2, NKS-1
    asm volatile("s_waitcnt vmcnt(2)" ::: "memory");
    asm volatile("s_barrier" ::: "memory");
    COMPUTE_STEP(NKS - 2);
    asm volatile("s_waitcnt vmcnt(0)" ::: "memory");
    asm volatile("s_barrier" ::: "memory");
    COMPUTE_STEP(NKS - 1);

    // epilogue: region-classified weighted square-sums (11 invariants)
    float fK = diag ? 1.f : 2.f;
    float vs[11] = {0,0,0,0,0,0,0,0,0,0,0};
#pragma unroll
    for (int m = 0; m < 4; ++m) {
#pragma unroll
        for (int qq = 0; qq < 4; ++qq) {
            int iw = wr4 * 64 + m * 16 + (lane >> 4) * 4 + qq;
            int gi = bi * 256 + iw;
            float di = drow[iw];
            float ui = urow[iw];
            bool iX = gi < N_ROWS;
            bool iG = !iX && (gi < N_ROWS + NCLS);
            bool iS = gi == N_ROWS + NCLS;
#pragma unroll
            for (int n = 0; n < 4; ++n) {
                int jw = wc4 * 64 + n * 16 + (lane & 15);
                int gj = bj * 256 + jw;
                float dj = dcol[jw];
                float k = acc[m][n][qq];
                float k2 = k * k;
                bool jX = gj < N_ROWS;
                bool jG = !jX && (gj < N_ROWS + NCLS);
                bool jS = gj == N_ROWS + NCLS;
                if (iX && jX) {
                    vs[0] += fK * k2;                        // Sum K^2
                    vs[1] += 0.5f * fK * (di + dj) * k2;     // Sum d_i K^2
                    vs[2] += fK * di * dj * k2;              // Sum d_i d_j K^2
                    vs[10] += fK * ui * ucol[jw] * k;        // u^T K u
                } else if (iX && jG) {
                    vs[3] += k2;                             // tr(TG)
                    vs[4] += di * k2;                        // tr(PG)
                } else if (iX && jS) {
                    vs[6] += k2;                             // s^T T s
                    vs[7] += di * k2;                        // s^T P s
                } else if (iG && jG) {
                    vs[5] += fK * k2;                        // ||G||^2
                } else if (iG && jS) {
                    vs[8] += k2;                             // s^T G s
                } else if (iS && jS) {
                    vs[9] += k;                              // s^T s
                }
            }
        }
    }
#pragma unroll
    for (int v = 0; v < 11; ++v) {
        float xv = vs[v];
        for (int off = 32; off; off >>= 1) xv += __shfl_down(xv, off);
        if (lane == 0) wred[w * 16 + v] = xv;
    }
    __syncthreads();
    if (tid < 11) {
        float sum = 0.f;
#pragma unroll
        for (int ww = 0; ww < 16; ++ww) sum += wred[ww * 16 + tid];
        atomicAdd(ssq + tid, sum);
    }
}

// --- final assembly --------------------------------------------------------
__global__ void k_final(const float* __restrict__ ssq, const float* __restrict__ nposf,
                        const int* __restrict__ hyper, const int* __restrict__ usemean,
                        const int* __restrict__ use_exp, float* __restrict__ out) {
    if (threadIdx.x != 0) return;
    double S0 = ssq[0], S1 = ssq[1], S2 = ssq[2], R2 = ssq[3], PG = ssq[4];
    double Q2 = ssq[5], TS = ssq[6], PS = ssq[7], GS = ssq[8], SS = ssq[9];
    double U2 = ssq[10];
    double Nf = (double)N_ROWS;
    double ni2 = S2 - 2.0 * PG + Q2;
    double nj2 = Nf * Nf * S0 + S2 + SS * SS + Q2 - 2.0 * Nf * S1
               - 2.0 * Nf * TS + 2.0 * Nf * R2 + 2.0 * PS - 2.0 * PG - 2.0 * GS;
    double trAB = Nf * S1 - S2 - PS + 2.0 * PG - Nf * R2 + GS - Q2;
    double d2 = ni2 - 2.0 * trAB + nj2;
    float norm_i = (float)sqrt(fmax(ni2, 0.0));
    float norm_j = (float)sqrt(fmax(nj2, 0.0));
    float h = (float)hyper[0], um = (float)usemean[0];
    float loss, dist;
    if (use_exp[0]) {
        dist = (float)exp(-sqrt(fmax(d2, 0.0)));
        loss = dist;
    } else {
        float mean_norm = sqrtf((float)C_DIM) * sqrtf(fmaxf((float)U2, 0.f));
        dist = norm_i - h * norm_j - um * mean_norm;
        loss = fmaxf(dist, 0.f);
    }
    out[0] = loss; out[1] = dist; out[2] = norm_i; out[3] = norm_j;
}

extern "C" void kernel_launch(void* const* d_in, const int* in_sizes, int n_in,
                              void* d_out, int out_size, void* d_ws, size_t ws_size,
                              hipStream_t stream) {
    const float* x = (const float*)d_in[0];
    const int* t = (const int*)d_in[1];
    const int* hyper = (const int*)d_in[2];
    const int* usemean = (const int*)d_in[3];
    const int* use_exp = (const int*)d_in[4];
    float* out = (float*)d_out;

    unsigned char* xbf = (unsigned char*)d_ws;
    size_t xbf_bytes = (size_t)NRB * NKS * TSB;        // ~18.9 MB
    float* g     = (float*)(xbf + xbf_bytes);          // 256 x 2048
    float* s     = g + (size_t)NCLS * C_DIM;           // 2048
    float* ca    = s + C_DIM;                          // N
    float* cb    = ca + N_ROWS;                        // N
    float* dr    = cb + N_ROWS;                        // N
    float* ssq   = dr + N_ROWS;                        // 16
    float* nposf = ssq + 16;                           // 1

    // zero atomically-accumulated scalars (ssq + nposf contiguous)
    hipMemsetAsync(ssq, 0, 32 * sizeof(float), stream);

    k_scan_conv<<<NCLS, 256, 0, stream>>>(t, x, g, ca, cb, dr, nposf, xbf);
    k_colsum<<<C_DIM / 256, 256, 0, stream>>>(g, s);
    k_conv_ext<<<128, 256, 0, stream>>>(g, s, xbf);
    k_gram<<<NRB * (NRB + 1) / 2, 1024, 0, stream>>>(xbf, dr, ca, cb, nposf, ssq);
    k_final<<<1, 64, 0, stream>>>(ssq, nposf, hyper, usemean, use_exp, out);
}